// Round 1
// baseline (277.458 us; speedup 1.0000x reference)
//
#include <hip/hip_runtime.h>

#define NEG_W 8.0f
#define EPS 1e-7f
#define BLOCKS 2048
#define TPB 256

// Kernel 1: grid-stride over float4/int4, one log per element, per-block
// partial sum written as double to d_ws[blockIdx.x].
__global__ __launch_bounds__(TPB) void bce_partial(
    const float4* __restrict__ out4, const int4* __restrict__ tgt4,
    double* __restrict__ partials, int nvec) {
  float sum = 0.0f;
  const int stride = gridDim.x * blockDim.x;
  for (int i = blockIdx.x * blockDim.x + threadIdx.x; i < nvec; i += stride) {
    float4 o = out4[i];
    int4 t = tgt4[i];
    // loss = t==1 ? -log(o+eps) : -8*log(1-o+eps)
    // accumulate w*log(x); negate once at the end.
    float x0 = (t.x == 1) ? (o.x + EPS) : (1.0f - o.x + EPS);
    float w0 = (t.x == 1) ? 1.0f : NEG_W;
    float x1 = (t.y == 1) ? (o.y + EPS) : (1.0f - o.y + EPS);
    float w1 = (t.y == 1) ? 1.0f : NEG_W;
    float x2 = (t.z == 1) ? (o.z + EPS) : (1.0f - o.z + EPS);
    float w2 = (t.z == 1) ? 1.0f : NEG_W;
    float x3 = (t.w == 1) ? (o.w + EPS) : (1.0f - o.w + EPS);
    float w3 = (t.w == 1) ? 1.0f : NEG_W;
    sum = fmaf(w0, __logf(x0), sum);
    sum = fmaf(w1, __logf(x1), sum);
    sum = fmaf(w2, __logf(x2), sum);
    sum = fmaf(w3, __logf(x3), sum);
  }
  sum = -sum;

  // wave64 butterfly reduce
  for (int off = 32; off > 0; off >>= 1)
    sum += __shfl_down(sum, off, 64);

  __shared__ float wsum[TPB / 64];
  const int lane = threadIdx.x & 63;
  const int wid = threadIdx.x >> 6;
  if (lane == 0) wsum[wid] = sum;
  __syncthreads();
  if (threadIdx.x == 0) {
    float s = 0.0f;
    for (int w = 0; w < TPB / 64; ++w) s += wsum[w];
    partials[blockIdx.x] = (double)s;
  }
}

// Kernel 2: single block reduces BLOCKS doubles, writes mean as float.
__global__ __launch_bounds__(TPB) void bce_finalize(
    const double* __restrict__ partials, float* __restrict__ out, int nblocks,
    float inv_n) {
  double s = 0.0;
  for (int i = threadIdx.x; i < nblocks; i += TPB) s += partials[i];
  for (int off = 32; off > 0; off >>= 1)
    s += __shfl_down(s, off, 64);
  __shared__ double wsum[TPB / 64];
  const int lane = threadIdx.x & 63;
  const int wid = threadIdx.x >> 6;
  if (lane == 0) wsum[wid] = s;
  __syncthreads();
  if (threadIdx.x == 0) {
    double tot = 0.0;
    for (int w = 0; w < TPB / 64; ++w) tot += wsum[w];
    out[0] = (float)(tot * (double)inv_n);
  }
}

extern "C" void kernel_launch(void* const* d_in, const int* in_sizes, int n_in,
                              void* d_out, int out_size, void* d_ws, size_t ws_size,
                              hipStream_t stream) {
  const float4* out4 = (const float4*)d_in[0];
  const int4* tgt4 = (const int4*)d_in[1];
  const int n = in_sizes[0];
  const int nvec = n / 4;  // N = 33554432, divisible by 4
  double* partials = (double*)d_ws;

  bce_partial<<<BLOCKS, TPB, 0, stream>>>(out4, tgt4, partials, nvec);
  bce_finalize<<<1, TPB, 0, stream>>>(partials, (float*)d_out, BLOCKS,
                                      1.0f / (float)n);
}